// Round 1
// baseline (127.369 us; speedup 1.0000x reference)
//
#include <hip/hip_runtime.h>
#include <hip/hip_bf16.h>

// Problem geometry (fixed by the reference):
//   B=32, C=384, H=W=64 -> spatial = 4096 floats per (b,c) plane
//   R=8 reduced channels, combined = 24 values per batch
#define BATCH 32
#define CHAN 384
#define SPATIAL 4096
#define BC (BATCH * CHAN)        // 12288
#define RCH 8

// ---------------------------------------------------------------------------
// Kernel 1: fused global avg/max/min pool.
// One 256-thread block per (b,c) plane; plane is 4096 contiguous floats.
// Each thread loads 4 float4 (16 floats), reduces, then wave + LDS reduce.
// ws layout: [0,BC) = sum, [BC,2BC) = max, [2BC,3BC) = min
// ---------------------------------------------------------------------------
__global__ __launch_bounds__(256) void pool_kernel(const float* __restrict__ x,
                                                   float* __restrict__ ws) {
    const int bc = blockIdx.x;
    const float4* p4 = (const float4*)(x + (size_t)bc * SPATIAL);
    const int tid = threadIdx.x;

    float s = 0.0f;
    float mx = -__builtin_inff();
    float mn = __builtin_inff();
#pragma unroll
    for (int i = 0; i < 4; ++i) {
        float4 v = p4[tid + i * 256];
        s += (v.x + v.y) + (v.z + v.w);
        mx = fmaxf(mx, fmaxf(fmaxf(v.x, v.y), fmaxf(v.z, v.w)));
        mn = fminf(mn, fminf(fminf(v.x, v.y), fminf(v.z, v.w)));
    }
    // wave64 butterfly reduce
#pragma unroll
    for (int off = 32; off > 0; off >>= 1) {
        s += __shfl_down(s, off);
        mx = fmaxf(mx, __shfl_down(mx, off));
        mn = fminf(mn, __shfl_down(mn, off));
    }
    __shared__ float ss[4], sm[4], sn[4];
    const int wid = tid >> 6;
    const int lane = tid & 63;
    if (lane == 0) { ss[wid] = s; sm[wid] = mx; sn[wid] = mn; }
    __syncthreads();
    if (tid == 0) {
        float fs = (ss[0] + ss[1]) + (ss[2] + ss[3]);
        float fm = fmaxf(fmaxf(sm[0], sm[1]), fmaxf(sm[2], sm[3]));
        float fn = fminf(fminf(sn[0], sn[1]), fminf(sn[2], sn[3]));
        ws[bc] = fs;
        ws[BC + bc] = fm;
        ws[2 * BC + bc] = fn;
    }
}

// ---------------------------------------------------------------------------
// Kernel 2: tiny "bottleneck MLP" -> logits [B, C].
// One block per batch, 384 threads (= C).
//   combined[0..7]   = avg @ W1.T          (avg = sum/4096)
//   combined[8..15]  = grouped max conv: sum_g mx[r*48+g]*W2_1[r,g], * W2_2[r]
//   combined[16..23] = mn @ W3.T
//   logits[b,c] = sum_j combined[j] * Wfc[c,j]     (Wfc is [C, 24] row-major)
// ---------------------------------------------------------------------------
__global__ __launch_bounds__(CHAN) void logits_kernel(
    const float* __restrict__ pools,   // ws from kernel 1
    const float* __restrict__ W1,      // [8,384]
    const float* __restrict__ W2_1,    // [8,48]
    const float* __restrict__ W2_2,    // [8]
    const float* __restrict__ W3,      // [8,384]
    const float* __restrict__ Wfc,     // [384,24]
    float* __restrict__ logits)        // [B,C]
{
    const int b = blockIdx.x;
    const int tid = threadIdx.x;
    __shared__ float avg[CHAN], smx[CHAN], smn[CHAN], comb[3 * RCH];

    avg[tid] = pools[b * CHAN + tid] * (1.0f / (float)SPATIAL);
    smx[tid] = pools[BC + b * CHAN + tid];
    smn[tid] = pools[2 * BC + b * CHAN + tid];
    __syncthreads();

    if (tid < RCH) {                       // avg path: full 384-dot
        float a = 0.0f;
        for (int c = 0; c < CHAN; ++c) a += avg[c] * W1[tid * CHAN + c];
        comb[tid] = a;
    } else if (tid < 2 * RCH) {            // max path: grouped, 48-dot + scale
        const int r = tid - RCH;
        float a = 0.0f;
        for (int g = 0; g < CHAN / RCH; ++g)
            a += smx[r * (CHAN / RCH) + g] * W2_1[r * (CHAN / RCH) + g];
        comb[tid] = a * W2_2[r];
    } else if (tid < 3 * RCH) {            // min path: full 384-dot
        const int r = tid - 2 * RCH;
        float a = 0.0f;
        for (int c = 0; c < CHAN; ++c) a += smn[c] * W3[r * CHAN + c];
        comb[tid] = a;
    }
    __syncthreads();

    float l = 0.0f;
#pragma unroll
    for (int j = 0; j < 3 * RCH; ++j) l += comb[j] * Wfc[tid * (3 * RCH) + j];
    logits[b * CHAN + tid] = l;
}

// ---------------------------------------------------------------------------
// Kernel 3: out = sigmoid(x + logits[b,c]), elementwise, float4-vectorized.
// Channel plane = 4096 floats = 1024 float4 -> bc index = f4_idx >> 10.
// ---------------------------------------------------------------------------
__global__ __launch_bounds__(256) void add_sig_kernel(
    const float* __restrict__ x,
    const float* __restrict__ logits,
    float* __restrict__ out)
{
    const size_t n4 = (size_t)BC * (SPATIAL / 4);   // 12,582,912 float4
    size_t i = blockIdx.x * (size_t)blockDim.x + threadIdx.x;
    const size_t stride = gridDim.x * (size_t)blockDim.x;
    const float4* x4 = (const float4*)x;
    float4* o4 = (float4*)out;
    for (; i < n4; i += stride) {
        const int bc = (int)(i >> 10);
        const float l = logits[bc];
        float4 v = x4[i];
        float4 o;
        o.x = 1.0f / (1.0f + __expf(-(v.x + l)));
        o.y = 1.0f / (1.0f + __expf(-(v.y + l)));
        o.z = 1.0f / (1.0f + __expf(-(v.z + l)));
        o.w = 1.0f / (1.0f + __expf(-(v.w + l)));
        o4[i] = o;
    }
}

// ---------------------------------------------------------------------------
extern "C" void kernel_launch(void* const* d_in, const int* in_sizes, int n_in,
                              void* d_out, int out_size, void* d_ws, size_t ws_size,
                              hipStream_t stream) {
    const float* x    = (const float*)d_in[0];
    const float* W1   = (const float*)d_in[1];
    const float* W2_1 = (const float*)d_in[2];
    const float* W2_2 = (const float*)d_in[3];
    const float* W3   = (const float*)d_in[4];
    const float* Wfc  = (const float*)d_in[5];
    float* out = (float*)d_out;
    float* ws  = (float*)d_ws;          // needs 4*BC floats = 192 KiB
    float* logits = ws + 3 * BC;

    hipLaunchKernelGGL(pool_kernel, dim3(BC), dim3(256), 0, stream, x, ws);
    hipLaunchKernelGGL(logits_kernel, dim3(BATCH), dim3(CHAN), 0, stream,
                       ws, W1, W2_1, W2_2, W3, Wfc, logits);
    hipLaunchKernelGGL(add_sig_kernel, dim3(2048), dim3(256), 0, stream,
                       x, logits, out);
}

// Round 3
// 101.430 us; speedup vs baseline: 1.2557x; 1.2557x over previous
//
#include <hip/hip_runtime.h>
#include <hip/hip_bf16.h>

// Problem geometry (fixed by the reference):
//   B=32, C=384, H=W=64 -> spatial = 4096 floats per (b,c) plane
//   R=8 reduced channels, combined = 24 values per batch
#define BATCH 32
#define CHAN 384
#define SPATIAL 4096
#define BC (BATCH * CHAN)        // 12288
#define RCH 8
#define NCOMB (3 * RCH)          // 24

typedef float f32x4 __attribute__((ext_vector_type(4)));

// ---------------------------------------------------------------------------
// Kernel 1: fused global avg/max/min pool.
// One 256-thread block per (b,c) plane; plane is 4096 contiguous floats.
// Each thread loads 4 float4 (16 floats), reduces, then wave + LDS reduce.
// ws layout: [0,BC) = sum, [BC,2BC) = max, [2BC,3BC) = min
// Plain (caching) loads on purpose: x must stay L3-resident for kernel 3.
// ---------------------------------------------------------------------------
__global__ __launch_bounds__(256) void pool_kernel(const float* __restrict__ x,
                                                   float* __restrict__ ws) {
    const int bc = blockIdx.x;
    const f32x4* p4 = (const f32x4*)(x + (size_t)bc * SPATIAL);
    const int tid = threadIdx.x;

    float s = 0.0f;
    float mx = -__builtin_inff();
    float mn = __builtin_inff();
#pragma unroll
    for (int i = 0; i < 4; ++i) {
        f32x4 v = p4[tid + i * 256];
        s += (v.x + v.y) + (v.z + v.w);
        mx = fmaxf(mx, fmaxf(fmaxf(v.x, v.y), fmaxf(v.z, v.w)));
        mn = fminf(mn, fminf(fminf(v.x, v.y), fminf(v.z, v.w)));
    }
    // wave64 butterfly reduce
#pragma unroll
    for (int off = 32; off > 0; off >>= 1) {
        s += __shfl_down(s, off);
        mx = fmaxf(mx, __shfl_down(mx, off));
        mn = fminf(mn, __shfl_down(mn, off));
    }
    __shared__ float ss[4], sm[4], sn[4];
    const int wid = tid >> 6;
    const int lane = tid & 63;
    if (lane == 0) { ss[wid] = s; sm[wid] = mx; sn[wid] = mn; }
    __syncthreads();
    if (tid == 0) {
        float fs = (ss[0] + ss[1]) + (ss[2] + ss[3]);
        float fm = fmaxf(fmaxf(sm[0], sm[1]), fmaxf(sm[2], sm[3]));
        float fn = fminf(fminf(sn[0], sn[1]), fminf(sn[2], sn[3]));
        ws[bc] = fs;
        ws[BC + bc] = fm;
        ws[2 * BC + bc] = fn;
    }
}

// ---------------------------------------------------------------------------
// Kernel 2: tiny "bottleneck MLP" -> logits [B, C].  One block per batch,
// 384 threads. Fully parallel: 24 output groups x 16 lanes each.
//   group j in [0,8):   avg @ W1.T      (24 channels/lane, shfl_xor reduce)
//   group j in [8,16):  grouped max conv (3 elems/lane)  * W2_2
//   group j in [16,24): mn @ W3.T
// then all 384 threads: logits[b,c] = dot24(comb, Wfc[c,:]).
// ---------------------------------------------------------------------------
__global__ __launch_bounds__(CHAN) void logits_kernel(
    const float* __restrict__ pools,   // ws from kernel 1
    const float* __restrict__ W1,      // [8,384]
    const float* __restrict__ W2_1,    // [8,48]
    const float* __restrict__ W2_2,    // [8]
    const float* __restrict__ W3,      // [8,384]
    const float* __restrict__ Wfc,     // [384,24]
    float* __restrict__ logits)        // [B,C]
{
    const int b = blockIdx.x;
    const int tid = threadIdx.x;
    __shared__ float avg[CHAN], smx[CHAN], smn[CHAN], comb[NCOMB];

    avg[tid] = pools[b * CHAN + tid] * (1.0f / (float)SPATIAL);
    smx[tid] = pools[BC + b * CHAN + tid];
    smn[tid] = pools[2 * BC + b * CHAN + tid];
    __syncthreads();

    const int gid = tid >> 4;       // 0..23 output group
    const int l16 = tid & 15;       // lane within group
    float a = 0.0f;
    if (gid < RCH) {                // avg path: 384-dot, 24 elems/lane
        const int r = gid;
#pragma unroll
        for (int k = 0; k < CHAN / 16; ++k) {
            const int c = l16 + k * 16;
            a += avg[c] * W1[r * CHAN + c];
        }
    } else if (gid < 2 * RCH) {     // max path: grouped 48-dot, 3 elems/lane
        const int r = gid - RCH;
#pragma unroll
        for (int k = 0; k < 3; ++k) {
            const int g = l16 + k * 16;
            a += smx[r * (CHAN / RCH) + g] * W2_1[r * (CHAN / RCH) + g];
        }
    } else {                        // min path: 384-dot
        const int r = gid - 2 * RCH;
#pragma unroll
        for (int k = 0; k < CHAN / 16; ++k) {
            const int c = l16 + k * 16;
            a += smn[c] * W3[r * CHAN + c];
        }
    }
    // reduce within the 16-lane group (stays inside one wave: 16 | 64)
#pragma unroll
    for (int off = 8; off > 0; off >>= 1) a += __shfl_xor(a, off);
    if (l16 == 0) {
        if (gid >= RCH && gid < 2 * RCH) a *= W2_2[gid - RCH];
        comb[gid] = a;
    }
    __syncthreads();

    float l = 0.0f;
#pragma unroll
    for (int j = 0; j < NCOMB; ++j) l += comb[j] * Wfc[tid * NCOMB + j];
    logits[b * CHAN + tid] = l;
}

// ---------------------------------------------------------------------------
// Kernel 3: out = sigmoid(x + logits[b,c]), elementwise, float4-vectorized.
// Channel plane = 4096 floats = 1024 float4 -> bc index = f4_idx >> 10.
// x read is nontemporal (dead after this); out store is nontemporal
// (never re-read) so it doesn't churn L2/L3.
// ---------------------------------------------------------------------------
__global__ __launch_bounds__(256) void add_sig_kernel(
    const float* __restrict__ x,
    const float* __restrict__ logits,
    float* __restrict__ out)
{
    const size_t n4 = (size_t)BC * (SPATIAL / 4);   // 12,582,912 float4
    size_t i = blockIdx.x * (size_t)blockDim.x + threadIdx.x;
    const size_t stride = gridDim.x * (size_t)blockDim.x;
    const f32x4* x4 = (const f32x4*)x;
    f32x4* o4 = (f32x4*)out;
    for (; i < n4; i += stride) {
        const int bc = (int)(i >> 10);
        const float l = logits[bc];
        f32x4 v = __builtin_nontemporal_load(&x4[i]);
        f32x4 o;
        o.x = __builtin_amdgcn_rcpf(1.0f + __expf(-(v.x + l)));
        o.y = __builtin_amdgcn_rcpf(1.0f + __expf(-(v.y + l)));
        o.z = __builtin_amdgcn_rcpf(1.0f + __expf(-(v.z + l)));
        o.w = __builtin_amdgcn_rcpf(1.0f + __expf(-(v.w + l)));
        __builtin_nontemporal_store(o, &o4[i]);
    }
}

// ---------------------------------------------------------------------------
extern "C" void kernel_launch(void* const* d_in, const int* in_sizes, int n_in,
                              void* d_out, int out_size, void* d_ws, size_t ws_size,
                              hipStream_t stream) {
    const float* x    = (const float*)d_in[0];
    const float* W1   = (const float*)d_in[1];
    const float* W2_1 = (const float*)d_in[2];
    const float* W2_2 = (const float*)d_in[3];
    const float* W3   = (const float*)d_in[4];
    const float* Wfc  = (const float*)d_in[5];
    float* out = (float*)d_out;
    float* ws  = (float*)d_ws;          // needs 4*BC floats = 192 KiB
    float* logits = ws + 3 * BC;

    hipLaunchKernelGGL(pool_kernel, dim3(BC), dim3(256), 0, stream, x, ws);
    hipLaunchKernelGGL(logits_kernel, dim3(BATCH), dim3(CHAN), 0, stream,
                       ws, W1, W2_1, W2_2, W3, Wfc, logits);
    hipLaunchKernelGGL(add_sig_kernel, dim3(2048), dim3(256), 0, stream,
                       x, logits, out);
}